// Round 6
// baseline (198.718 us; speedup 1.0000x reference)
//
#include <hip/hip_runtime.h>

#define D 640
#define HID 64
#define NITER 64
#define ROWS 8           // rows per block; each of 4 waves owns 2 rows
#define BLOCK 256

// ---- DPP wave64 reductions (VALU pipe only) ----
#define DPP_ADD_STEP(v, ctrl, rmask)                                          \
    v += __builtin_bit_cast(float, __builtin_amdgcn_update_dpp(               \
             0, __builtin_bit_cast(int, v), ctrl, rmask, 0xf, true))
#define DPP_MAX_STEP(v, ctrl, rmask)                                          \
    v = fmaxf(v, __builtin_bit_cast(float, __builtin_amdgcn_update_dpp(       \
             __builtin_bit_cast(int, v), __builtin_bit_cast(int, v),          \
             ctrl, rmask, 0xf, false)))

// Two interleaved reduce chains (rows A and B) -> 2x ILP on the serial path.
__device__ __forceinline__ void wave_sum_dpp2(float& a, float& b) {
    DPP_ADD_STEP(a, 0x111, 0xf);  DPP_ADD_STEP(b, 0x111, 0xf);
    DPP_ADD_STEP(a, 0x112, 0xf);  DPP_ADD_STEP(b, 0x112, 0xf);
    DPP_ADD_STEP(a, 0x114, 0xf);  DPP_ADD_STEP(b, 0x114, 0xf);
    DPP_ADD_STEP(a, 0x118, 0xf);  DPP_ADD_STEP(b, 0x118, 0xf);
    DPP_ADD_STEP(a, 0x142, 0xa);  DPP_ADD_STEP(b, 0x142, 0xa);
    DPP_ADD_STEP(a, 0x143, 0xc);  DPP_ADD_STEP(b, 0x143, 0xc);
    a = __builtin_bit_cast(float,
        __builtin_amdgcn_readlane(__builtin_bit_cast(int, a), 63));
    b = __builtin_bit_cast(float,
        __builtin_amdgcn_readlane(__builtin_bit_cast(int, b), 63));
}
__device__ __forceinline__ void wave_max_dpp2(float& a, float& b) {
    DPP_MAX_STEP(a, 0x111, 0xf);  DPP_MAX_STEP(b, 0x111, 0xf);
    DPP_MAX_STEP(a, 0x112, 0xf);  DPP_MAX_STEP(b, 0x112, 0xf);
    DPP_MAX_STEP(a, 0x114, 0xf);  DPP_MAX_STEP(b, 0x114, 0xf);
    DPP_MAX_STEP(a, 0x118, 0xf);  DPP_MAX_STEP(b, 0x118, 0xf);
    DPP_MAX_STEP(a, 0x142, 0xa);  DPP_MAX_STEP(b, 0x142, 0xa);
    DPP_MAX_STEP(a, 0x143, 0xc);  DPP_MAX_STEP(b, 0x143, 0xc);
    a = __builtin_bit_cast(float,
        __builtin_amdgcn_readlane(__builtin_bit_cast(int, a), 63));
    b = __builtin_bit_cast(float,
        __builtin_amdgcn_readlane(__builtin_bit_cast(int, b), 63));
}

// 4 blocks/CU (16 waves/CU); VGPR cap 128.
__global__ __launch_bounds__(BLOCK, 4) void dimmask_kernel(
    const float* __restrict__ x, const float* __restrict__ W1,
    const float* __restrict__ b1, const float* __restrict__ W2,
    const float* __restrict__ b2, float* __restrict__ out)
{
    constexpr float INV_T = 1.0f / 0.07f;
    constexpr float LOG2E = 1.4426950408889634f;
    constexpr float TEMP  = 0.07f;
    constexpr float KPOW  = 100.0f / 7.0f;    // (1-y)^KPOW per step

    __shared__ float lds_a[ROWS][D];          // x rows, then ht
    __shared__ float lds_part[4][ROWS][HID];
    __shared__ float lds_hid[ROWS][HID];

    const int tid  = threadIdx.x;
    const int row0 = blockIdx.x * ROWS;

    // ---- stage x rows into LDS (coalesced float4) ----
    {
        const float4* xv  = (const float4*)(x + (size_t)row0 * D);
        float4*       lxv = (float4*)(&lds_a[0][0]);
        for (int i = tid; i < ROWS * D / 4; i += BLOCK) lxv[i] = xv[i];
    }
    __syncthreads();

    // ---- GEMM1: hid[r][k] = relu(sum_t x[r][t]*W1[t][k] + b1[k]) ----
    {
        const int k = tid & 63, c = tid >> 6;
        float acc[ROWS];
#pragma unroll
        for (int r = 0; r < ROWS; ++r) acc[r] = 0.f;
        const int q0 = c * 40;                 // float4 index base (c*160/4)
#pragma unroll 2
        for (int q = q0; q < q0 + 40; ++q) {
            const int tb = q * 4;
            float w0 = W1[(tb + 0) * HID + k];
            float w1 = W1[(tb + 1) * HID + k];
            float w2 = W1[(tb + 2) * HID + k];
            float w3 = W1[(tb + 3) * HID + k];
#pragma unroll
            for (int r = 0; r < ROWS; ++r) {
                float4 xa = ((const float4*)&lds_a[r][0])[q];
                acc[r] += xa.x * w0 + xa.y * w1 + xa.z * w2 + xa.w * w3;
            }
        }
#pragma unroll
        for (int r = 0; r < ROWS; ++r) lds_part[c][r][k] = acc[r];
    }
    __syncthreads();
    for (int idx = tid; idx < ROWS * HID; idx += BLOCK) {
        const int r = idx >> 6, k = idx & 63;
        float s = lds_part[0][r][k] + lds_part[1][r][k]
                + lds_part[2][r][k] + lds_part[3][r][k] + b1[k];
        lds_hid[r][k] = fmaxf(s, 0.f);
    }
    __syncthreads();

    // ---- GEMM2: ht[r][j] = -h*log2e/T over dead x in lds_a ----
    for (int j = tid; j < D; j += BLOCK) {
        float acc[ROWS];
#pragma unroll
        for (int r = 0; r < ROWS; ++r) acc[r] = 0.f;
#pragma unroll 2
        for (int k4 = 0; k4 < HID / 4; ++k4) {
            const int kb = k4 * 4;
            float w0 = W2[(kb + 0) * D + j];
            float w1 = W2[(kb + 1) * D + j];
            float w2 = W2[(kb + 2) * D + j];
            float w3 = W2[(kb + 3) * D + j];
#pragma unroll
            for (int r = 0; r < ROWS; ++r) {
                float4 hh = ((const float4*)&lds_hid[r][0])[k4];
                acc[r] += hh.x * w0 + hh.y * w1 + hh.z * w2 + hh.w * w3;
            }
        }
        float bb = b2[j];
#pragma unroll
        for (int r = 0; r < ROWS; ++r)
            lds_a[r][j] = -(acc[r] + bb) * (LOG2E * INV_T);
    }
    __syncthreads();

    // ---- Phase B: one wave per TWO rows; uniform exp/log recurrence ----
    // e_j <- e_j * (1-y_j)^k  computed as  e * exp2(k * log2(1-y)).
    // 5 VALU + 2 trans per element, branchless, valid for ALL y in [0,1]
    // (f guarded > 0 against rcp overshoot; y->1 gives e->0 correctly).
    const int w = tid >> 6, l = tid & 63;
    const int rA = 2 * w, rB = 2 * w + 1;
    float eA[10], eB[10];
    float hmaxA, hmaxB;
    {
        float htA[10], htB[10];
        float ha = -3.0e38f, hb = -3.0e38f;
#pragma unroll
        for (int u = 0; u < 10; ++u) {
            htA[u] = lds_a[rA][l + 64 * u];
            htB[u] = lds_a[rB][l + 64 * u];
            ha = fmaxf(ha, htA[u]);
            hb = fmaxf(hb, htB[u]);
        }
        wave_max_dpp2(ha, hb);
        hmaxA = ha; hmaxB = hb;
#pragma unroll
        for (int u = 0; u < 10; ++u) {
            eA[u] = __builtin_amdgcn_exp2f(fmaxf(htA[u] - ha, -80.f));
            eB[u] = __builtin_amdgcn_exp2f(fmaxf(htB[u] - hb, -80.f));
        }
    }

    float saccA = ((eA[0] + eA[1]) + (eA[2] + eA[3]))
                + ((eA[4] + eA[5]) + (eA[6] + eA[7])) + (eA[8] + eA[9]);
    float saccB = ((eB[0] + eB[1]) + (eB[2] + eB[3]))
                + ((eB[4] + eB[5]) + (eB[6] + eB[7])) + (eB[8] + eB[9]);

    for (int it = 0; it < NITER; ++it) {
        float sA = saccA, sB = saccB;
        wave_sum_dpp2(sA, sB);
        float rsA = __builtin_amdgcn_rcpf(sA);
        float rsB = __builtin_amdgcn_rcpf(sB);
        float nsA = 0.f, nsB = 0.f;
#pragma unroll
        for (int u = 0; u < 10; ++u) {
            float fA = fmaxf(fmaf(eA[u], -rsA, 1.0f), 1e-35f);
            float fB = fmaxf(fmaf(eB[u], -rsB, 1.0f), 1e-35f);
            float gA = __builtin_amdgcn_exp2f(KPOW * __builtin_amdgcn_logf(fA));
            float gB = __builtin_amdgcn_exp2f(KPOW * __builtin_amdgcn_logf(fB));
            eA[u] *= gA;
            eB[u] *= gB;
            nsA += eA[u];
            nsB += eB[u];
        }
        saccA = nsA; saccB = nsB;
    }

    // ---- epilogue: m = (e/E)^T = exp2(T*(log2(e) - c)), c = clamp(ht-hmax) ----
#pragma unroll
    for (int pr = 0; pr < 2; ++pr) {
        const int r = (pr == 0) ? rA : rB;
        const float hm = (pr == 0) ? hmaxA : hmaxB;
        float* e = (pr == 0) ? eA : eB;
        const float* xrow = x + (size_t)(row0 + r) * D;
        float* orow = out + (size_t)(row0 + r) * D;
#pragma unroll
        for (int u = 0; u < 10; ++u) {
            const int j = l + 64 * u;
            float c = fmaxf(lds_a[r][j] - hm, -80.f);
            float m = __builtin_amdgcn_exp2f(
                TEMP * (__builtin_amdgcn_logf(e[u]) - c));
            orow[j] = m * xrow[j];
        }
    }
}

extern "C" void kernel_launch(void* const* d_in, const int* in_sizes, int n_in,
                              void* d_out, int out_size, void* d_ws, size_t ws_size,
                              hipStream_t stream) {
    const float* x  = (const float*)d_in[0];
    const float* W1 = (const float*)d_in[1];
    const float* b1 = (const float*)d_in[2];
    const float* W2 = (const float*)d_in[3];
    const float* b2 = (const float*)d_in[4];
    float* out = (float*)d_out;

    const int B = in_sizes[0] / D;            // 8192
    dim3 grid(B / ROWS), block(BLOCK);
    hipLaunchKernelGGL(dimmask_kernel, grid, block, 0, stream, x, W1, b1, W2, b2, out);
}